// Round 1
// baseline (312.482 us; speedup 1.0000x reference)
//
#include <hip/hip_runtime.h>
#include <hip/hip_bf16.h>

namespace {

constexpr int T_STEPS = 256;
constexpr int HD = 50;   // hidden size
constexpr int HP = 64;   // padded hidden
constexpr int KST = 72;  // LDS row stride in bf16 elems (16B-aligned rows, breaks bank patterns)
constexpr int BT = 16;   // batch tile per block

typedef __attribute__((ext_vector_type(8))) short bf16x8;
typedef __attribute__((ext_vector_type(4))) float f32x4;

__device__ __forceinline__ unsigned short f2bf(float x) {
  __hip_bfloat16 h = __float2bfloat16(x);
  return *reinterpret_cast<unsigned short*>(&h);
}
__device__ __forceinline__ float bf2f(unsigned short u) {
  __hip_bfloat16 h;
  *reinterpret_cast<unsigned short*>(&h) = u;
  return __bfloat162float(h);
}
__device__ __forceinline__ float fast_tanh(float x) {
  float e = __expf(2.0f * x);
  return 1.0f - 2.0f * __builtin_amdgcn_rcpf(e + 1.0f);
}

// Orientation: D[i][b] = sum_k W[i][k] * h[b][k]
//   A (M=i, K)  = weights, static in VGPRs (A[m=lane&15][k=quad*8+j])
//   B (K, N=b)  = h state, from LDS      (B[k=quad*8+j][n=lane&15])
//   C/D         = row(i)=quad*4+reg, col(b)=lane&15
__global__ __launch_bounds__(256, 1) void rnn3_kernel(
    const float* __restrict__ x,
    const float* __restrict__ Wih1, const float* __restrict__ Whh1,
    const float* __restrict__ bih1, const float* __restrict__ bhh1,
    const float* __restrict__ Wih2, const float* __restrict__ Whh2,
    const float* __restrict__ bih2, const float* __restrict__ bhh2,
    const float* __restrict__ Wih3, const float* __restrict__ Whh3,
    const float* __restrict__ bih3, const float* __restrict__ bhh3,
    const float* __restrict__ fcw, const float* __restrict__ fcb,
    float* __restrict__ out) {
  // h state, ping-pong: [pp][layer][hi/lo][b*KST + k] (bf16 bits), zero-padded k>=HD
  __shared__ unsigned short hbuf[2][3][2][BT * KST];
  // weight staging scratch: [hi/lo][i*KST + k]
  __shared__ unsigned short scr[2][HP * KST];

  const int tid = threadIdx.x;
  const int wv = tid >> 6;        // wave id = M-tile (i in [16*wv, 16*wv+16))
  const int lane = tid & 63;
  const int quad = lane >> 4;
  const int l15 = lane & 15;
  const int b0 = blockIdx.x * BT;

  // zero both ping-pong h buffers (initial state h_{-1}=0; also the i>=HD pad)
  {
    unsigned int* hz = reinterpret_cast<unsigned int*>(&hbuf[0][0][0][0]);
    const int n = 2 * 3 * 2 * BT * KST / 2;  // uint count
    for (int i = tid; i < n; i += 256) hz[i] = 0u;
  }

  // ---- stage the five 50x50 matrices, split fp32 -> bf16 hi/lo, preload A-frags to regs ----
  const float* mats[5] = {Whh1, Wih2, Whh2, Wih3, Whh3};
  bf16x8 afh[5][2], afl[5][2];  // [matrix][kstep]
#pragma unroll
  for (int m = 0; m < 5; ++m) {
    __syncthreads();  // scratch free (and, first time, hbuf zeros ordered)
    const float* W = mats[m];
    for (int idx = tid; idx < HP * HP; idx += 256) {
      int i = idx >> 6, k = idx & 63;
      float v = (i < HD && k < HD) ? W[i * HD + k] : 0.0f;
      unsigned short hi = f2bf(v);
      float rem = v - bf2f(hi);
      scr[0][i * KST + k] = hi;
      scr[1][i * KST + k] = f2bf(rem);
    }
    __syncthreads();
    const int arow = 16 * wv + l15;  // A-frag row mapping
    const unsigned short* ph = &scr[0][arow * KST + 8 * quad];
    const unsigned short* pl = &scr[1][arow * KST + 8 * quad];
    afh[m][0] = *reinterpret_cast<const bf16x8*>(ph);
    afh[m][1] = *reinterpret_cast<const bf16x8*>(ph + 32);
    afl[m][0] = *reinterpret_cast<const bf16x8*>(pl);
    afl[m][1] = *reinterpret_cast<const bf16x8*>(pl + 32);
  }

  // ---- per-lane C-row constants (i = ic + r), zero-padded past HD ----
  const int ic = 16 * wv + 4 * quad;
  float wx0[4], wx1[4], bs[3][4];
#pragma unroll
  for (int r = 0; r < 4; ++r) {
    int i = ic + r;
    bool v = i < HD;
    wx0[r] = v ? Wih1[i * 2 + 0] : 0.0f;
    wx1[r] = v ? Wih1[i * 2 + 1] : 0.0f;
    bs[0][r] = v ? (bih1[i] + bhh1[i]) : 0.0f;
    bs[1][r] = v ? (bih2[i] + bhh2[i]) : 0.0f;
    bs[2][r] = v ? (bih3[i] + bhh3[i]) : 0.0f;
  }

  // x for this lane's batch column (C col = b = l15); fp32, handled on VALU (exact)
  const float* xb = x + (size_t)(b0 + l15) * (T_STEPS * 2);
  float2 xpref = *reinterpret_cast<const float2*>(xb);  // t=0 prefetch

  __syncthreads();

  // ---- diagonal pipeline: iter s computes h1_s, h2_{s-1}, h3_{s-2} ----
  for (int s = 0; s < T_STEPS + 2; ++s) {
    const int cur = s & 1;
    const int nxt = cur ^ 1;

    // read all B-frags (h state) for this iteration into regs
    bf16x8 bh[3][2][2];  // [layer][kstep][hi/lo]
#pragma unroll
    for (int L = 0; L < 3; ++L)
#pragma unroll
      for (int ks = 0; ks < 2; ++ks)
#pragma unroll
        for (int h = 0; h < 2; ++h)
          bh[L][ks][h] = *reinterpret_cast<const bf16x8*>(
              &hbuf[cur][L][h][l15 * KST + 32 * ks + 8 * quad]);

    float2 xc = xpref;
    int snext = (s + 1 < T_STEPS) ? s + 1 : T_STEPS - 1;
    xpref = *reinterpret_cast<const float2*>(xb + snext * 2);  // hide global latency

    const bool a1 = (s < T_STEPS);
    const bool a2 = (s >= 1) && (s <= T_STEPS);
    const bool a3 = (s >= 2);

    auto store_h = [&](int L, f32x4 C) {
      unsigned short hi[4], lo[4];
#pragma unroll
      for (int r = 0; r < 4; ++r) {
        float h = fast_tanh(C[r]);
        hi[r] = f2bf(h);
        lo[r] = f2bf(h - bf2f(hi[r]));
      }
      unsigned int h01 = (unsigned int)hi[0] | ((unsigned int)hi[1] << 16);
      unsigned int h23 = (unsigned int)hi[2] | ((unsigned int)hi[3] << 16);
      unsigned int l01 = (unsigned int)lo[0] | ((unsigned int)lo[1] << 16);
      unsigned int l23 = (unsigned int)lo[2] | ((unsigned int)lo[3] << 16);
      // lane holds 4 consecutive i for one b -> packed 8B writes
      *reinterpret_cast<uint2*>(&hbuf[nxt][L][0][l15 * KST + ic]) = make_uint2(h01, h23);
      *reinterpret_cast<uint2*>(&hbuf[nxt][L][1][l15 * KST + ic]) = make_uint2(l01, l23);
    };

    if (a1) {  // layer 1 at t = s : h1_s = tanh(b1 + Wih1 x_s + Whh1 h1_{s-1})
      f32x4 C1;
#pragma unroll
      for (int r = 0; r < 4; ++r) C1[r] = bs[0][r] + wx0[r] * xc.x + wx1[r] * xc.y;
#pragma unroll
      for (int ks = 0; ks < 2; ++ks) {
        C1 = __builtin_amdgcn_mfma_f32_16x16x32_bf16(afh[0][ks], bh[0][ks][0], C1, 0, 0, 0);
        C1 = __builtin_amdgcn_mfma_f32_16x16x32_bf16(afh[0][ks], bh[0][ks][1], C1, 0, 0, 0);
        C1 = __builtin_amdgcn_mfma_f32_16x16x32_bf16(afl[0][ks], bh[0][ks][0], C1, 0, 0, 0);
      }
      store_h(0, C1);
    }
    if (a2) {  // layer 2 at t = s-1 : uses h1_{s-1} (bh[0]) and h2_{s-2} (bh[1])
      f32x4 C2;
#pragma unroll
      for (int r = 0; r < 4; ++r) C2[r] = bs[1][r];
#pragma unroll
      for (int ks = 0; ks < 2; ++ks) {
        C2 = __builtin_amdgcn_mfma_f32_16x16x32_bf16(afh[1][ks], bh[0][ks][0], C2, 0, 0, 0);
        C2 = __builtin_amdgcn_mfma_f32_16x16x32_bf16(afh[1][ks], bh[0][ks][1], C2, 0, 0, 0);
        C2 = __builtin_amdgcn_mfma_f32_16x16x32_bf16(afl[1][ks], bh[0][ks][0], C2, 0, 0, 0);
        C2 = __builtin_amdgcn_mfma_f32_16x16x32_bf16(afh[2][ks], bh[1][ks][0], C2, 0, 0, 0);
        C2 = __builtin_amdgcn_mfma_f32_16x16x32_bf16(afh[2][ks], bh[1][ks][1], C2, 0, 0, 0);
        C2 = __builtin_amdgcn_mfma_f32_16x16x32_bf16(afl[2][ks], bh[1][ks][0], C2, 0, 0, 0);
      }
      store_h(1, C2);
    }
    if (a3) {  // layer 3 at t = s-2 : uses h2_{s-2} (bh[1]) and h3_{s-3} (bh[2])
      f32x4 C3;
#pragma unroll
      for (int r = 0; r < 4; ++r) C3[r] = bs[2][r];
#pragma unroll
      for (int ks = 0; ks < 2; ++ks) {
        C3 = __builtin_amdgcn_mfma_f32_16x16x32_bf16(afh[3][ks], bh[1][ks][0], C3, 0, 0, 0);
        C3 = __builtin_amdgcn_mfma_f32_16x16x32_bf16(afh[3][ks], bh[1][ks][1], C3, 0, 0, 0);
        C3 = __builtin_amdgcn_mfma_f32_16x16x32_bf16(afl[3][ks], bh[1][ks][0], C3, 0, 0, 0);
        C3 = __builtin_amdgcn_mfma_f32_16x16x32_bf16(afh[4][ks], bh[2][ks][0], C3, 0, 0, 0);
        C3 = __builtin_amdgcn_mfma_f32_16x16x32_bf16(afh[4][ks], bh[2][ks][1], C3, 0, 0, 0);
        C3 = __builtin_amdgcn_mfma_f32_16x16x32_bf16(afl[4][ks], bh[2][ks][0], C3, 0, 0, 0);
      }
      store_h(2, C3);
    }
    __syncthreads();  // single barrier: writes to nxt visible before next iter reads
  }

  // ---- fc epilogue: h3_255 landed in pp buffer 0 (written at s=257 -> nxt=0) ----
  if (tid < BT * 2) {
    int b = tid >> 1, o = tid & 1;
    const unsigned short* h3h = &hbuf[0][2][0][b * KST];
    const unsigned short* h3l = &hbuf[0][2][1][b * KST];
    float acc = fcb[o];
    for (int i = 0; i < HD; ++i)
      acc += fcw[o * HD + i] * (bf2f(h3h[i]) + bf2f(h3l[i]));
    out[(size_t)(b0 + b) * 2 + o] = acc;
  }
}

}  // namespace

extern "C" void kernel_launch(void* const* d_in, const int* in_sizes, int n_in,
                              void* d_out, int out_size, void* d_ws, size_t ws_size,
                              hipStream_t stream) {
  const float* x = (const float*)d_in[0];
  const float* Wih1 = (const float*)d_in[1];
  const float* Whh1 = (const float*)d_in[2];
  const float* bih1 = (const float*)d_in[3];
  const float* bhh1 = (const float*)d_in[4];
  const float* Wih2 = (const float*)d_in[5];
  const float* Whh2 = (const float*)d_in[6];
  const float* bih2 = (const float*)d_in[7];
  const float* bhh2 = (const float*)d_in[8];
  const float* Wih3 = (const float*)d_in[9];
  const float* Whh3 = (const float*)d_in[10];
  const float* bih3 = (const float*)d_in[11];
  const float* bhh3 = (const float*)d_in[12];
  const float* fcw = (const float*)d_in[13];
  const float* fcb = (const float*)d_in[14];

  rnn3_kernel<<<4096 / BT, 256, 0, stream>>>(x, Wih1, Whh1, bih1, bhh1,
                                             Wih2, Whh2, bih2, bhh2,
                                             Wih3, Whh3, bih3, bhh3,
                                             fcw, fcb, (float*)d_out);
}

// Round 2
// 283.331 us; speedup vs baseline: 1.1029x; 1.1029x over previous
//
#include <hip/hip_runtime.h>
#include <hip/hip_bf16.h>

namespace {

constexpr int T_STEPS = 256;
constexpr int HD = 50;   // hidden size
constexpr int HP = 64;   // padded hidden
constexpr int KST = 72;  // LDS row stride in bf16 elems (2-way bank alias only — free per m136)
constexpr int BT = 16;   // batch tile per block
constexpr int NW = 12;   // waves per block: (layer, M-tile)
constexpr int NTHR = NW * 64;  // 768

typedef __attribute__((ext_vector_type(8))) short bf16x8;
typedef __attribute__((ext_vector_type(4))) float f32x4;

__device__ __forceinline__ unsigned short f2bf(float x) {
  __hip_bfloat16 h = __float2bfloat16(x);
  return *reinterpret_cast<unsigned short*>(&h);
}
__device__ __forceinline__ float bf2f(unsigned short u) {
  __hip_bfloat16 h;
  *reinterpret_cast<unsigned short*>(&h) = u;
  return __bfloat162float(h);
}
__device__ __forceinline__ float fast_tanh(float x) {
  float e = __expf(2.0f * x);
  return 1.0f - 2.0f * __builtin_amdgcn_rcpf(e + 1.0f);
}

// Orientation: D[i][b] = sum_k W[i][k] * h[b][k]
//   A (M=i, K)  = weights, static in VGPRs (A[m=lane&15][k=quad*8+j])
//   B (K, N=b)  = h state, from LDS      (B[k=quad*8+j][n=lane&15])
//   C/D         = row(i)=quad*4+reg, col(b)=lane&15
// Wave w = (L = w>>2, wv = w&3): layer L, output rows [16*wv, 16*wv+16).
// 12 waves = 3 waves/SIMD so stalled chains in one wave are hidden by others.
__global__ __launch_bounds__(NTHR, 3) void rnn3_kernel(
    const float* __restrict__ x,
    const float* __restrict__ Wih1, const float* __restrict__ Whh1,
    const float* __restrict__ bih1, const float* __restrict__ bhh1,
    const float* __restrict__ Wih2, const float* __restrict__ Whh2,
    const float* __restrict__ bih2, const float* __restrict__ bhh2,
    const float* __restrict__ Wih3, const float* __restrict__ Whh3,
    const float* __restrict__ bih3, const float* __restrict__ bhh3,
    const float* __restrict__ fcw, const float* __restrict__ fcb,
    float* __restrict__ out) {
  // h state, ping-pong: [pp][layer][hi/lo][b*KST + k] (bf16 bits), zero-padded k>=HD
  __shared__ unsigned short hbuf[2][3][2][BT * KST];
  // weight staging scratch: [hi/lo][i*KST + k]
  __shared__ unsigned short scr[2][HP * KST];

  const int tid = threadIdx.x;
  const int w = tid >> 6;
  const int myL = w >> 2;         // layer 0..2
  const int wv = w & 3;           // M-tile
  const int lane = tid & 63;
  const int quad = lane >> 4;
  const int l15 = lane & 15;
  const int b0 = blockIdx.x * BT;

  // zero both ping-pong h buffers (initial state h_{-1}=0; also the i>=HD pad)
  {
    unsigned int* hz = reinterpret_cast<unsigned int*>(&hbuf[0][0][0][0]);
    const int n = 2 * 3 * 2 * BT * KST / 2;
    for (int i = tid; i < n; i += NTHR) hz[i] = 0u;
  }

  // ---- stage the five 50x50 matrices, split fp32 -> bf16 hi/lo ----
  // Each wave keeps only its own layer's A-frags:
  //   L0: slot0 = Whh1;  L1: slot0 = Wih2, slot1 = Whh2;  L2: slot0 = Wih3, slot1 = Whh3
  const float* mats[5] = {Whh1, Wih2, Whh2, Wih3, Whh3};
  constexpr int matL[5] = {0, 1, 1, 2, 2};
  constexpr int matS[5] = {0, 0, 1, 0, 1};
  bf16x8 wAh[2][2], wAl[2][2];  // [slot][kstep]
#pragma unroll
  for (int sl = 0; sl < 2; ++sl)
#pragma unroll
    for (int ks = 0; ks < 2; ++ks) { wAh[sl][ks] = bf16x8(0); wAl[sl][ks] = bf16x8(0); }

  const int arow = 16 * wv + l15;  // A-frag row mapping
#pragma unroll
  for (int m = 0; m < 5; ++m) {
    __syncthreads();  // scratch free (and, first time, hbuf zeros ordered)
    const float* W = mats[m];
    for (int idx = tid; idx < HP * HP; idx += NTHR) {
      int i = idx >> 6, k = idx & 63;
      float v = (i < HD && k < HD) ? W[i * HD + k] : 0.0f;
      unsigned short hi = f2bf(v);
      float rem = v - bf2f(hi);
      scr[0][i * KST + k] = hi;
      scr[1][i * KST + k] = f2bf(rem);
    }
    __syncthreads();
    if (myL == matL[m]) {
      const unsigned short* ph = &scr[0][arow * KST + 8 * quad];
      const unsigned short* pl = &scr[1][arow * KST + 8 * quad];
      wAh[matS[m]][0] = *reinterpret_cast<const bf16x8*>(ph);
      wAh[matS[m]][1] = *reinterpret_cast<const bf16x8*>(ph + 32);
      wAl[matS[m]][0] = *reinterpret_cast<const bf16x8*>(pl);
      wAl[matS[m]][1] = *reinterpret_cast<const bf16x8*>(pl + 32);
    }
  }

  // ---- per-lane C-row constants (i = ic + r), zero-padded past HD ----
  const int ic = 16 * wv + 4 * quad;
  const float* bi = (myL == 0) ? bih1 : (myL == 1) ? bih2 : bih3;
  const float* bh = (myL == 0) ? bhh1 : (myL == 1) ? bhh2 : bhh3;
  float wx0[4], wx1[4], bs[4];
#pragma unroll
  for (int r = 0; r < 4; ++r) {
    int i = ic + r;
    bool v = i < HD;
    bs[r] = v ? (bi[i] + bh[i]) : 0.0f;
    wx0[r] = (v && myL == 0) ? Wih1[i * 2 + 0] : 0.0f;
    wx1[r] = (v && myL == 0) ? Wih1[i * 2 + 1] : 0.0f;
  }

  // x for this lane's batch column (C col = b = l15); fp32 on VALU (exact); L0 waves only
  const float* xb = x + (size_t)(b0 + l15) * (T_STEPS * 2);
  float2 xpref = make_float2(0.f, 0.f);
  if (myL == 0) xpref = *reinterpret_cast<const float2*>(xb);

  // input-layer indices into hbuf for this wave's two matmuls
  const int inA = (myL == 2) ? 1 : 0;  // L0,L1 read h1; L2 reads h2
  const int inB = myL;                 // L1 reads h2; L2 reads h3 (unused for L0)

  __syncthreads();

  // ---- diagonal pipeline: iter s computes h1_s, h2_{s-1}, h3_{s-2} ----
  for (int s = 0; s < T_STEPS + 2; ++s) {
    const int cur = s & 1;
    const int nxt = cur ^ 1;

    const bool act = (myL == 0) ? (s < T_STEPS)
                   : (myL == 1) ? (s >= 1 && s <= T_STEPS)
                                : (s >= 2);

    if (act) {
      // read this wave's B-frags
      bf16x8 bA[2][2], bB[2][2];  // [kstep][hi/lo]
#pragma unroll
      for (int ks = 0; ks < 2; ++ks)
#pragma unroll
        for (int h = 0; h < 2; ++h) {
          bA[ks][h] = *reinterpret_cast<const bf16x8*>(
              &hbuf[cur][inA][h][l15 * KST + 32 * ks + 8 * quad]);
          if (myL > 0)
            bB[ks][h] = *reinterpret_cast<const bf16x8*>(
                &hbuf[cur][inB][h][l15 * KST + 32 * ks + 8 * quad]);
        }

      f32x4 Ca, Cb;
      if (myL == 0) {
        float2 xc = xpref;
        int snext = (s + 1 < T_STEPS) ? s + 1 : T_STEPS - 1;
        xpref = *reinterpret_cast<const float2*>(xb + snext * 2);  // hide global latency
#pragma unroll
        for (int r = 0; r < 4; ++r) Ca[r] = bs[r] + wx0[r] * xc.x + wx1[r] * xc.y;
      } else {
#pragma unroll
        for (int r = 0; r < 4; ++r) { Ca[r] = bs[r]; Cb[r] = 0.0f; }
      }

      // two independent 6-deep MFMA chains (ILP within wave)
#pragma unroll
      for (int ks = 0; ks < 2; ++ks) {
        Ca = __builtin_amdgcn_mfma_f32_16x16x32_bf16(wAh[0][ks], bA[ks][0], Ca, 0, 0, 0);
        Ca = __builtin_amdgcn_mfma_f32_16x16x32_bf16(wAh[0][ks], bA[ks][1], Ca, 0, 0, 0);
        Ca = __builtin_amdgcn_mfma_f32_16x16x32_bf16(wAl[0][ks], bA[ks][0], Ca, 0, 0, 0);
      }
      if (myL > 0) {
#pragma unroll
        for (int ks = 0; ks < 2; ++ks) {
          Cb = __builtin_amdgcn_mfma_f32_16x16x32_bf16(wAh[1][ks], bB[ks][0], Cb, 0, 0, 0);
          Cb = __builtin_amdgcn_mfma_f32_16x16x32_bf16(wAh[1][ks], bB[ks][1], Cb, 0, 0, 0);
          Cb = __builtin_amdgcn_mfma_f32_16x16x32_bf16(wAl[1][ks], bB[ks][0], Cb, 0, 0, 0);
        }
#pragma unroll
        for (int r = 0; r < 4; ++r) Ca[r] += Cb[r];
      }

      // tanh, split to hi/lo bf16, packed 8B writes (lane holds 4 consecutive i for one b)
      unsigned short hi[4], lo[4];
#pragma unroll
      for (int r = 0; r < 4; ++r) {
        float h = fast_tanh(Ca[r]);
        hi[r] = f2bf(h);
        lo[r] = f2bf(h - bf2f(hi[r]));
      }
      unsigned int h01 = (unsigned int)hi[0] | ((unsigned int)hi[1] << 16);
      unsigned int h23 = (unsigned int)hi[2] | ((unsigned int)hi[3] << 16);
      unsigned int l01 = (unsigned int)lo[0] | ((unsigned int)lo[1] << 16);
      unsigned int l23 = (unsigned int)lo[2] | ((unsigned int)lo[3] << 16);
      *reinterpret_cast<uint2*>(&hbuf[nxt][myL][0][l15 * KST + ic]) = make_uint2(h01, h23);
      *reinterpret_cast<uint2*>(&hbuf[nxt][myL][1][l15 * KST + ic]) = make_uint2(l01, l23);
    }
    __syncthreads();  // single barrier per iter: writes to nxt visible before next reads
  }

  // ---- fc epilogue: h3_255 landed in pp buffer 0 (written at s=257 -> nxt=0) ----
  if (tid < BT * 2) {
    int b = tid >> 1, o = tid & 1;
    const unsigned short* h3h = &hbuf[0][2][0][b * KST];
    const unsigned short* h3l = &hbuf[0][2][1][b * KST];
    float acc = fcb[o];
    for (int i = 0; i < HD; ++i)
      acc += fcw[o * HD + i] * (bf2f(h3h[i]) + bf2f(h3l[i]));
    out[(size_t)(b0 + b) * 2 + o] = acc;
  }
}

}  // namespace

extern "C" void kernel_launch(void* const* d_in, const int* in_sizes, int n_in,
                              void* d_out, int out_size, void* d_ws, size_t ws_size,
                              hipStream_t stream) {
  const float* x = (const float*)d_in[0];
  const float* Wih1 = (const float*)d_in[1];
  const float* Whh1 = (const float*)d_in[2];
  const float* bih1 = (const float*)d_in[3];
  const float* bhh1 = (const float*)d_in[4];
  const float* Wih2 = (const float*)d_in[5];
  const float* Whh2 = (const float*)d_in[6];
  const float* bih2 = (const float*)d_in[7];
  const float* bhh2 = (const float*)d_in[8];
  const float* Wih3 = (const float*)d_in[9];
  const float* Whh3 = (const float*)d_in[10];
  const float* bih3 = (const float*)d_in[11];
  const float* bhh3 = (const float*)d_in[12];
  const float* fcw = (const float*)d_in[13];
  const float* fcb = (const float*)d_in[14];

  rnn3_kernel<<<4096 / BT, NTHR, 0, stream>>>(x, Wih1, Whh1, bih1, bhh1,
                                              Wih2, Whh2, bih2, bhh2,
                                              Wih3, Whh3, bih3, bhh3,
                                              fcw, fcb, (float*)d_out);
}